// Round 6
// baseline (249.441 us; speedup 1.0000x reference)
//
#include <hip/hip_runtime.h>
#include <hip/hip_fp16.h>

#define PENALTY_N 0.1f
#define CP 33344         // nodes per partition (mult of 64); P=3 covers 100,032
#define MAX_BPP 80       // slices; grid = 3*Bpp = 240 blocks ~= 1/CU
#define ABLK 1024        // threads per block, scatter

// ---------------------------------------------------------------------------
// Phase A: compute per-edge transfer once; emit packed 8B records
//   rec64 = src(17) | dst(17)<<17 | half(t)<<34
// The only kernel doing random gathers (12.8M, irreducible without a sort).
// Also zeroes the scalar accumulator out[nN].
// ---------------------------------------------------------------------------
__global__ __launch_bounds__(256, 8) void compute_t_kernel(
    const int* __restrict__ src_idx,
    const int* __restrict__ dst_idx,
    const float* __restrict__ w,
    const float* __restrict__ traffic,
    uint2* __restrict__ rec,
    float* __restrict__ out_scalar,
    int nE) {
    const int tid = blockIdx.x * blockDim.x + threadIdx.x;
    const int stride = gridDim.x * blockDim.x;
    if (blockIdx.x == 0 && threadIdx.x == 0) *out_scalar = 0.0f;

    const int nvec = nE >> 2;
    const int4* __restrict__ s4p = (const int4*)src_idx;
    const int4* __restrict__ d4p = (const int4*)dst_idx;
    const float4* __restrict__ w4p = (const float4*)w;
    uint4* __restrict__ r4p = (uint4*)rec;   // 2 records per uint4

    for (int v = tid; v < nvec; v += stride) {
        int4 s = s4p[v];
        int4 d = d4p[v];
        float4 ww = w4p[v];
        // 8 independent gathers issued before any use
        float a0 = traffic[s.x], a1 = traffic[s.y];
        float a2 = traffic[s.z], a3 = traffic[s.w];
        float b0 = traffic[d.x], b1 = traffic[d.y];
        float b2 = traffic[d.z], b3 = traffic[d.w];
        float t0 = fabsf(a0 - b0) * (PENALTY_N * ww.x);
        float t1 = fabsf(a1 - b1) * (PENALTY_N * ww.y);
        float t2 = fabsf(a2 - b2) * (PENALTY_N * ww.z);
        float t3 = fabsf(a3 - b3) * (PENALTY_N * ww.w);
        unsigned long long h0 = __half_as_ushort(__float2half_rn(t0));
        unsigned long long h1 = __half_as_ushort(__float2half_rn(t1));
        unsigned long long h2 = __half_as_ushort(__float2half_rn(t2));
        unsigned long long h3 = __half_as_ushort(__float2half_rn(t3));
        unsigned long long r0 = (unsigned long long)(unsigned)s.x |
                                ((unsigned long long)(unsigned)d.x << 17) | (h0 << 34);
        unsigned long long r1 = (unsigned long long)(unsigned)s.y |
                                ((unsigned long long)(unsigned)d.y << 17) | (h1 << 34);
        unsigned long long r2 = (unsigned long long)(unsigned)s.z |
                                ((unsigned long long)(unsigned)d.z << 17) | (h2 << 34);
        unsigned long long r3 = (unsigned long long)(unsigned)s.w |
                                ((unsigned long long)(unsigned)d.w << 17) | (h3 << 34);
        uint4 q0, q1;
        q0.x = (unsigned)r0; q0.y = (unsigned)(r0 >> 32);
        q0.z = (unsigned)r1; q0.w = (unsigned)(r1 >> 32);
        q1.x = (unsigned)r2; q1.y = (unsigned)(r2 >> 32);
        q1.z = (unsigned)r3; q1.w = (unsigned)(r3 >> 32);
        r4p[2 * v] = q0;
        r4p[2 * v + 1] = q1;
    }
    for (int e = (nvec << 2) + tid; e < nE; e += stride) {
        int si = src_idx[e], di = dst_idx[e];
        float t = fabsf(traffic[si] - traffic[di]) * (PENALTY_N * w[e]);
        unsigned long long h = __half_as_ushort(__float2half_rn(t));
        unsigned long long r = (unsigned long long)(unsigned)si |
                               ((unsigned long long)(unsigned)di << 17) | (h << 34);
        rec[e] = make_uint2((unsigned)r, (unsigned)(r >> 32));
    }
}

// ---------------------------------------------------------------------------
// Phase B: partitioned scatter over packed records, trio-L2 scheduled.
// The 3 partition-blocks sharing an edge slice land on the SAME XCD
// (blockIdx%8 round-robin model) and read identical addresses near-lockstep,
// so 2/3 of stream reads hit that XCD's L2 instead of L3. 2x unrolled for
// 4 outstanding stream loads/wave. Requires Bpp % 8 == 0, grid = 3*Bpp.
// ---------------------------------------------------------------------------
__global__ __launch_bounds__(ABLK, 4) void part_scatter_kernel(
    const uint2* __restrict__ rec,
    float* __restrict__ scratch,   // [P][Bpp][CP]
    int nE, int nN, int Bpp) {
    __shared__ float hist[CP];

    const int g = blockIdx.x;
    const int trio = g >> 3;                 // 0 .. 3*Bpp/8-1
    const int p = trio % 3;                  // partition
    const int slice = (g & 7) + 8 * (trio / 3);   // 0..Bpp-1
    const int lo = p * CP;
    const unsigned csz = (unsigned)min(CP, nN - lo);
    const int tid = threadIdx.x;

    {
        float4* h4 = (float4*)hist;
        for (int i = tid; i < CP / 4; i += ABLK)
            h4[i] = make_float4(0.f, 0.f, 0.f, 0.f);
    }
    __syncthreads();

    const int nvec = nE >> 2;
    const uint4* __restrict__ r4p = (const uint4*)rec;
    const int stride = Bpp * ABLK;

#define PROC_REC(LOW, HIGH)                                                   \
    {                                                                         \
        unsigned lw = (LOW), hw = (HIGH);                                     \
        unsigned srcI = lw & 0x1FFFFu;                                        \
        unsigned dstI = ((lw >> 17) | (hw << 15)) & 0x1FFFFu;                 \
        float t = __half2float(__ushort_as_half((unsigned short)(hw >> 2)));  \
        unsigned u;                                                           \
        u = srcI - (unsigned)lo; if (u < csz) atomicAdd(&hist[u], -t);        \
        u = dstI - (unsigned)lo; if (u < csz) atomicAdd(&hist[u],  t);        \
    }

    int v = slice * ABLK + tid;
    for (; v + stride < nvec; v += 2 * stride) {
        uint4 q0 = r4p[2 * v];
        uint4 q1 = r4p[2 * v + 1];
        int v2 = v + stride;
        uint4 q2 = r4p[2 * v2];
        uint4 q3 = r4p[2 * v2 + 1];
        PROC_REC(q0.x, q0.y) PROC_REC(q0.z, q0.w)
        PROC_REC(q1.x, q1.y) PROC_REC(q1.z, q1.w)
        PROC_REC(q2.x, q2.y) PROC_REC(q2.z, q2.w)
        PROC_REC(q3.x, q3.y) PROC_REC(q3.z, q3.w)
    }
    for (; v < nvec; v += stride) {
        uint4 q0 = r4p[2 * v];
        uint4 q1 = r4p[2 * v + 1];
        PROC_REC(q0.x, q0.y) PROC_REC(q0.z, q0.w)
        PROC_REC(q1.x, q1.y) PROC_REC(q1.z, q1.w)
    }
    for (int e = (nvec << 2) + slice * ABLK + tid; e < nE; e += stride) {
        uint2 r = rec[e];
        PROC_REC(r.x, r.y)
    }
#undef PROC_REC

    __syncthreads();
    float* dst = scratch + (size_t)(p * Bpp + slice) * CP;
    {
        const int n4 = (int)(csz >> 2);
        float4* d4 = (float4*)dst;
        const float4* h4 = (const float4*)hist;
        for (int i = tid; i < n4; i += ABLK) d4[i] = h4[i];
        for (int i = (n4 << 2) + tid; i < (int)csz; i += ABLK) dst[i] = hist[i];
    }
}

// ---------------------------------------------------------------------------
// Phase C: per-node sum of Bpp private copies + base traffic; writes
// new_traffic and fuses the service-efficiency reduction.
// ---------------------------------------------------------------------------
__global__ __launch_bounds__(256) void part_reduce_kernel(
    const float* __restrict__ scratch,
    const float* __restrict__ traffic,
    const float* __restrict__ yield_rate,
    const float* __restrict__ cost,
    float* __restrict__ out,        // [nN] new_traffic, out[nN] scalar
    int nN, int Bpp) {
    const int tid = blockIdx.x * blockDim.x + threadIdx.x;
    const int stride = gridDim.x * blockDim.x;

    float acc = 0.0f;
    for (int i = tid; i < nN; i += stride) {
        int p = i / CP;
        int off = i - p * CP;
        const float* base = scratch + (size_t)p * Bpp * CP + off;

        float s0 = traffic[i], s1 = 0.0f, s2 = 0.0f, s3 = 0.0f;
        int b = 0;
        for (; b + 8 <= Bpp; b += 8) {
            const float* q = base + (size_t)b * CP;
            float a0 = q[0 * (size_t)CP];
            float a1 = q[1 * (size_t)CP];
            float a2 = q[2 * (size_t)CP];
            float a3 = q[3 * (size_t)CP];
            float a4 = q[4 * (size_t)CP];
            float a5 = q[5 * (size_t)CP];
            float a6 = q[6 * (size_t)CP];
            float a7 = q[7 * (size_t)CP];
            s0 += a0 + a4;
            s1 += a1 + a5;
            s2 += a2 + a6;
            s3 += a3 + a7;
        }
        for (; b < Bpp; ++b) s0 += base[(size_t)b * CP];
        float s = (s0 + s1) + (s2 + s3);
        out[i] = s;
        acc = fmaf(yield_rate[i], s, acc) - cost[i];
    }

    #pragma unroll
    for (int off = 32; off > 0; off >>= 1) acc += __shfl_down(acc, off, 64);

    __shared__ float wsum[4];
    const int lane = threadIdx.x & 63;
    const int wid = threadIdx.x >> 6;
    if (lane == 0) wsum[wid] = acc;
    __syncthreads();
    if (threadIdx.x == 0)
        atomicAdd(&out[nN], wsum[0] + wsum[1] + wsum[2] + wsum[3]);
}

// ---------------------------------------------------------------------------
// Fallback path (ws too small / nN too large for 17-bit packing).
// ---------------------------------------------------------------------------
__global__ void init_out_kernel(const float* __restrict__ traffic,
                                float* __restrict__ out, int nN) {
    int i = blockIdx.x * blockDim.x + threadIdx.x;
    if (i < nN) out[i] = traffic[i];
    else if (i == nN) out[i] = 0.0f;
}

__global__ __launch_bounds__(256) void edge_scatter_kernel(
    const int* __restrict__ src_idx, const int* __restrict__ dst_idx,
    const float* __restrict__ w, const float* __restrict__ traffic,
    float* __restrict__ out, int nE) {
    const int tid = blockIdx.x * blockDim.x + threadIdx.x;
    const int stride = gridDim.x * blockDim.x;
    for (int e = tid; e < nE; e += stride) {
        int s = src_idx[e];
        int d = dst_idx[e];
        float t = fabsf(traffic[s] - traffic[d]) * (PENALTY_N * w[e]);
        atomicAdd(&out[s], -t);
        atomicAdd(&out[d], t);
    }
}

__global__ __launch_bounds__(256) void reduce_kernel(
    const float* __restrict__ new_traffic, const float* __restrict__ yield_rate,
    const float* __restrict__ cost, float* __restrict__ total, int nN) {
    const int tid = blockIdx.x * blockDim.x + threadIdx.x;
    const int stride = gridDim.x * blockDim.x;
    float acc = 0.0f;
    for (int i = tid; i < nN; i += stride)
        acc = fmaf(yield_rate[i], new_traffic[i], acc) - cost[i];
    #pragma unroll
    for (int off = 32; off > 0; off >>= 1) acc += __shfl_down(acc, off, 64);
    __shared__ float wsum[4];
    const int lane = threadIdx.x & 63;
    const int wid = threadIdx.x >> 6;
    if (lane == 0) wsum[wid] = acc;
    __syncthreads();
    if (threadIdx.x == 0)
        atomicAdd(total, wsum[0] + wsum[1] + wsum[2] + wsum[3]);
}

// ---------------------------------------------------------------------------
extern "C" void kernel_launch(void* const* d_in, const int* in_sizes, int n_in,
                              void* d_out, int out_size, void* d_ws, size_t ws_size,
                              hipStream_t stream) {
    const int* edge_index = (const int*)d_in[0];     // (2, E) flat
    const float* edge_weight = (const float*)d_in[1];
    const float* nodes_yield = (const float*)d_in[2];
    const float* nodes_traffic = (const float*)d_in[3];
    const float* nodes_cost = (const float*)d_in[4];
    float* out = (float*)d_out;

    const int nE = in_sizes[1];
    const int nN = in_sizes[2];
    const int* src_idx = edge_index;
    const int* dst_idx = edge_index + nE;

    const int P = (nN + CP - 1) / CP;   // 3 for nN=100K

    // ws layout: [ rec (uint2, nE, 256B-aligned) | scratch (P*Bpp*CP floats) ]
    size_t rbytes = (((size_t)nE * sizeof(uint2)) + 255) & ~(size_t)255;
    size_t rem = (ws_size > rbytes) ? (ws_size - rbytes) : 0;
    int Bpp = (int)(rem / ((size_t)P * CP * sizeof(float)));
    if (Bpp > MAX_BPP) Bpp = MAX_BPP;
    Bpp &= ~7;  // trio mapping needs Bpp % 8 == 0

    if (Bpp >= 16 && P == 3 && nN <= 131072) {
        uint2* rec = (uint2*)d_ws;
        float* scratch = (float*)((char*)d_ws + rbytes);

        compute_t_kernel<<<2048, 256, 0, stream>>>(
            src_idx, dst_idx, edge_weight, nodes_traffic,
            rec, out + nN, nE);
        part_scatter_kernel<<<3 * Bpp, ABLK, 0, stream>>>(
            rec, scratch, nE, nN, Bpp);
        int rgrid = (nN + 255) / 256;
        part_reduce_kernel<<<rgrid, 256, 0, stream>>>(
            scratch, nodes_traffic, nodes_yield, nodes_cost, out, nN, Bpp);
    } else {
        int grid = (nN + 1 + 255) / 256;
        init_out_kernel<<<grid, 256, 0, stream>>>(nodes_traffic, out, nN);
        edge_scatter_kernel<<<2048, 256, 0, stream>>>(src_idx, dst_idx,
                                                      edge_weight, nodes_traffic,
                                                      out, nE);
        reduce_kernel<<<256, 256, 0, stream>>>(out, nodes_yield, nodes_cost,
                                               out + nN, nN);
    }
}